// Round 1
// baseline (295.657 us; speedup 1.0000x reference)
//
#include <hip/hip_runtime.h>
#include <hip/hip_bf16.h>

#define B_   2
#define N_   2048
#define C_   1152
#define NH   16
#define HD   72
#define HDP  96    // padded head dim for QK^T (3 x K=32)
#define HDV  80    // padded head dim for PV (5 x 16)
#define KQKV 3456

typedef __attribute__((ext_vector_type(8))) short bf16x8;
typedef __attribute__((ext_vector_type(4))) float f32x4;

__device__ __forceinline__ short f2bf(float f) {
  union { float fv; unsigned int u; } v; v.fv = f;
  unsigned int r = v.u + 0x7fffu + ((v.u >> 16) & 1u);
  return (short)(r >> 16);
}

__device__ __forceinline__ void gload_lds16(const short* g, short* l) {
  __builtin_amdgcn_global_load_lds(
      (const __attribute__((address_space(1))) unsigned int*)g,
      (__attribute__((address_space(3))) unsigned int*)l, 16, 0, 0);
}

// ---------------- elementwise f32 -> bf16 (vectorized x4) ----------------
__global__ void cvt_bf16(const float* __restrict__ in, short* __restrict__ out, int n4) {
  int i = blockIdx.x * 256 + threadIdx.x;
  if (i < n4) {
    float4 v = ((const float4*)in)[i];
    short4 s;
    s.x = f2bf(v.x); s.y = f2bf(v.y); s.z = f2bf(v.z); s.w = f2bf(v.w);
    ((short4*)out)[i] = s;
  }
}

// ---------------- transpose + convert: src (R x Cc f32) -> dst (Cc x R bf16) ----------------
__global__ void transpose_cvt(const float* __restrict__ src, short* __restrict__ dst,
                              int R, int Cc) {
  __shared__ float tile[32][33];
  const int c0 = blockIdx.x * 32, r0 = blockIdx.y * 32;
  const int tx = threadIdx.x, ty = threadIdx.y;  // 32 x 8
  for (int i = ty; i < 32; i += 8)
    tile[i][tx] = src[(long)(r0 + i) * Cc + c0 + tx];
  __syncthreads();
  for (int i = ty; i < 32; i += 8)
    dst[(long)(c0 + i) * R + r0 + tx] = f2bf(tile[tx][i]);
}

// ---------------- GEMM: A (MxK bf16 rm) * Bt (NxK bf16 rm)^T -> C (MxN f32), opt bias ----------------
// m97 structure: 128x128 tile, BK=32, 4 waves of 64x64, global_load_lds width 16.
template<bool BIAS>
__global__ __launch_bounds__(256, 2) void gemm_bt(
    const short* __restrict__ A, const short* __restrict__ Bt,
    float* __restrict__ C, const float* __restrict__ bias,
    int M, int N, int K) {
  __shared__ __align__(16) short As[128 * 32];
  __shared__ __align__(16) short Bs[128 * 32];
  const int t = threadIdx.x;
  const int lane = t & 63, wid = t >> 6;
  const int fr = lane & 15, fq = lane >> 4;
  const int bm = blockIdx.y, bn = blockIdx.x;
  const int wr = (wid >> 1) * 64, wc = (wid & 1) * 64;

  const int srow = t >> 2;
  const int scol = (t & 3) * 8;
  const short* Ag = A + (long)(bm * 128 + srow) * K + scol;
  const short* Bg = Bt + (long)(bn * 128 + srow) * K + scol;
  short* Asl = As + t * 8;
  short* Bsl = Bs + t * 8;

  f32x4 acc[4][4] = {};

  for (int kt = 0; kt < K; kt += 32) {
    gload_lds16(Ag + kt,                 Asl);
    gload_lds16(Ag + kt + (long)64 * K,  Asl + 2048);
    gload_lds16(Bg + kt,                 Bsl);
    gload_lds16(Bg + kt + (long)64 * K,  Bsl + 2048);
    asm volatile("s_waitcnt vmcnt(0)" ::: "memory");
    __syncthreads();

    bf16x8 af[4], bf[4];
    #pragma unroll
    for (int i = 0; i < 4; ++i)
      af[i] = *(const bf16x8*)(As + (wr + i * 16 + fr) * 32 + fq * 8);
    #pragma unroll
    for (int j = 0; j < 4; ++j)
      bf[j] = *(const bf16x8*)(Bs + (wc + j * 16 + fr) * 32 + fq * 8);
    #pragma unroll
    for (int i = 0; i < 4; ++i)
      #pragma unroll
      for (int j = 0; j < 4; ++j)
        acc[i][j] = __builtin_amdgcn_mfma_f32_16x16x32_bf16(af[i], bf[j], acc[i][j], 0, 0, 0);
    __syncthreads();
  }

  // epilogue: D layout row=(lane>>4)*4+r, col=lane&15  [m89-verified]
  #pragma unroll
  for (int i = 0; i < 4; ++i) {
    #pragma unroll
    for (int j = 0; j < 4; ++j) {
      const long row0 = (long)bm * 128 + wr + i * 16 + fq * 4;
      const int col = bn * 128 + wc + j * 16 + fr;
      const float bv = BIAS ? bias[col] : 0.f;
      #pragma unroll
      for (int r = 0; r < 4; ++r)
        C[(row0 + r) * (long)N + col] = acc[i][j][r] + bv;
    }
  }
}

// ---------------- RoPE + repack ----------------
// QKV f32 (B*N, 3456) -> Qp (b,h,n,96) bf16 (rope, *1/sqrt(72), pad 0)
//                        Kp (b,h,n,96) bf16 (rope, pad 0)
//                        Vt (b,h,80,2048) bf16 (transposed, pad 0)
__global__ __launch_bounds__(256) void rope_pack(
    const float* __restrict__ QKV, short* __restrict__ Qp,
    short* __restrict__ Kp, short* __restrict__ Vt) {
  const int blk = blockIdx.x;
  const int nt = blk & 15;
  const int h = (blk >> 4) & 15;
  const int b = blk >> 8;
  const int t = threadIdx.x;
  const int n0 = nt * 128;
  const float qscale = 0.117851130198f;  // 1/sqrt(72)
  const float PI = 3.14159265358979323846f;

  for (int which = 0; which < 2; ++which) {
    short* dst = which ? Kp : Qp;
    const float sc = which ? 1.0f : qscale;
    for (int idx = t; idx < 128 * HDP; idx += 256) {
      const int r = idx / HDP;
      const int d = idx - r * HDP;
      const int n = n0 + r;
      float val = 0.f;
      if (d < HD) {
        const long rowoff = ((long)(b * N_ + n)) * KQKV + which * C_ + h * HD;
        const float x = QKV[rowoff + d];
        if (d < 48) {
          float pos;
          if (d < 16)      pos = -1.f + (2.f / 7.f)  * (float)(n >> 8);
          else if (d < 32) pos = -1.f + (2.f / 15.f) * (float)((n >> 4) & 15);
          else             pos = -1.f + (2.f / 15.f) * (float)(n & 15);
          const int fi = (d & 15) >> 1;
          const float base = (1.f + (127.f / 7.f) * (float)fi) * PI;
          const float f = pos * base;
          const float cs = cosf(f), sn = sinf(f);
          const float partner = QKV[rowoff + (d ^ 1)];
          val = (d & 1) ? (x * cs + partner * sn) : (x * cs - partner * sn);
        } else {
          val = x;
        }
        val *= sc;
      }
      dst[(((long)(b * NH + h)) * N_ + n) * HDP + d] = f2bf(val);
    }
  }

  // V transpose via LDS tile (coalesced both sides)
  __shared__ short vt[128][81];
  for (int idx = t; idx < 128 * HDV; idx += 256) {
    const int r = idx / HDV, d = idx - r * HDV;
    float v = 0.f;
    if (d < HD) v = QKV[((long)(b * N_ + n0 + r)) * KQKV + 2 * C_ + h * HD + d];
    vt[r][d] = f2bf(v);
  }
  __syncthreads();
  for (int idx = t; idx < HDV * 128; idx += 256) {
    const int d = idx >> 7, nn = idx & 127;
    Vt[(((long)(b * NH + h)) * HDV + d) * N_ + n0 + nn] = vt[nn][d];
  }
}

// ---------------- flash attention ----------------
// per block: (b, h, 128-row q-tile). 4 waves x 32 q-rows. K-tiles of 128 keys.
__global__ __launch_bounds__(256) void attn(
    const short* __restrict__ Qp, const short* __restrict__ Kp,
    const short* __restrict__ Vt, short* __restrict__ Aproj) {
  __shared__ __align__(16) short Ks[128 * HDP];  // 24 KB
  __shared__ __align__(16) short Vs[HDV * 128];  // 20 KB
  __shared__ __align__(16) short Ps[128 * 128];  // 32 KB
  const int blk = blockIdx.x;
  const int qt = blk & 15;
  const int h = (blk >> 4) & 15;
  const int b = blk >> 8;
  const int t = threadIdx.x, lane = t & 63, wid = t >> 6;
  const int fr = lane & 15, fq = lane >> 4;

  const long bh = (long)(b * NH + h);
  const short* Qg = Qp + (bh * N_ + qt * 128) * HDP;
  const short* Kg = Kp + bh * N_ * HDP;
  const short* Vg = Vt + bh * HDV * N_;

  // Q fragments held in registers for the whole kernel
  bf16x8 qf[2][3];
  #pragma unroll
  for (int i = 0; i < 2; ++i)
    #pragma unroll
    for (int kk = 0; kk < 3; ++kk)
      qf[i][kk] = *(const bf16x8*)(Qg + (wid * 32 + i * 16 + fr) * HDP + kk * 32 + fq * 8);

  f32x4 accO[2][5] = {};
  float m_[2][4], l_[2][4];
  #pragma unroll
  for (int i = 0; i < 2; ++i)
    #pragma unroll
    for (int r = 0; r < 4; ++r) { m_[i][r] = -1e30f; l_[i][r] = 0.f; }

  for (int kt2 = 0; kt2 < 16; ++kt2) {
    // stage K tile (contiguous 24KB) and V^T tile (80 rows x 256B)
    const short* Ksrc = Kg + (long)kt2 * 128 * HDP;
    #pragma unroll
    for (int it = 0; it < 6; ++it)
      gload_lds16(Ksrc + (it * 256 + t) * 8, Ks + (it * 256 + t) * 8);
    {
      const int d = t >> 4, co = (t & 15) * 8;
      #pragma unroll
      for (int it = 0; it < 5; ++it)
        gload_lds16(Vg + (long)(it * 16 + d) * N_ + kt2 * 128 + co,
                    Vs + (it * 16 + d) * 128 + co);
    }
    asm volatile("s_waitcnt vmcnt(0)" ::: "memory");
    __syncthreads();

    // S = Q K^T : 32 q-rows x 128 keys per wave
    f32x4 s[2][8] = {};
    #pragma unroll
    for (int kk = 0; kk < 3; ++kk) {
      #pragma unroll
      for (int j = 0; j < 8; ++j) {
        bf16x8 kf = *(const bf16x8*)(Ks + (j * 16 + fr) * HDP + kk * 32 + fq * 8);
        s[0][j] = __builtin_amdgcn_mfma_f32_16x16x32_bf16(qf[0][kk], kf, s[0][j], 0, 0, 0);
        s[1][j] = __builtin_amdgcn_mfma_f32_16x16x32_bf16(qf[1][kk], kf, s[1][j], 0, 0, 0);
      }
    }

    // online softmax (rows of a frag: row = fq*4 + r; cols across lanes fr + 16j)
    #pragma unroll
    for (int i = 0; i < 2; ++i) {
      #pragma unroll
      for (int r = 0; r < 4; ++r) {
        float pm = s[i][0][r];
        #pragma unroll
        for (int j = 1; j < 8; ++j) pm = fmaxf(pm, s[i][j][r]);
        #pragma unroll
        for (int off = 1; off < 16; off <<= 1)
          pm = fmaxf(pm, __shfl_xor(pm, off, 16));
        const float mnew = fmaxf(m_[i][r], pm);
        const float esc = __expf(m_[i][r] - mnew);
        m_[i][r] = mnew;
        float psum = 0.f;
        #pragma unroll
        for (int j = 0; j < 8; ++j) {
          const float p = __expf(s[i][j][r] - mnew);
          psum += p;
          Ps[(wid * 32 + i * 16 + fq * 4 + r) * 128 + j * 16 + fr] = f2bf(p);
        }
        #pragma unroll
        for (int off = 1; off < 16; off <<= 1)
          psum += __shfl_xor(psum, off, 16);
        l_[i][r] = l_[i][r] * esc + psum;
        #pragma unroll
        for (int jd = 0; jd < 5; ++jd)
          accO[i][jd][r] *= esc;
      }
    }

    asm volatile("s_waitcnt lgkmcnt(0)" ::: "memory");

    // O += P V  (P rows are wave-private in Ps; Vs shared, staged above)
    #pragma unroll
    for (int kk4 = 0; kk4 < 4; ++kk4) {
      bf16x8 pf[2];
      #pragma unroll
      for (int i = 0; i < 2; ++i)
        pf[i] = *(const bf16x8*)(Ps + (wid * 32 + i * 16 + fr) * 128 + kk4 * 32 + fq * 8);
      #pragma unroll
      for (int jd = 0; jd < 5; ++jd) {
        bf16x8 vf = *(const bf16x8*)(Vs + (jd * 16 + fr) * 128 + kk4 * 32 + fq * 8);
        accO[0][jd] = __builtin_amdgcn_mfma_f32_16x16x32_bf16(pf[0], vf, accO[0][jd], 0, 0, 0);
        accO[1][jd] = __builtin_amdgcn_mfma_f32_16x16x32_bf16(pf[1], vf, accO[1][jd], 0, 0, 0);
      }
    }
    __syncthreads();  // all waves done with Ks/Vs before next stage
  }

  // epilogue: o/l -> bf16 -> Aproj[(b,n), h*72+d]
  #pragma unroll
  for (int i = 0; i < 2; ++i) {
    #pragma unroll
    for (int r = 0; r < 4; ++r) {
      const float inv = 1.f / l_[i][r];
      const long n = qt * 128 + wid * 32 + i * 16 + fq * 4 + r;
      #pragma unroll
      for (int jd = 0; jd < 5; ++jd) {
        const int d = jd * 16 + fr;
        if (d < HD)
          Aproj[((long)b * N_ + n) * C_ + h * HD + d] = f2bf(accO[i][jd][r] * inv);
      }
    }
  }
}

extern "C" void kernel_launch(void* const* d_in, const int* in_sizes, int n_in,
                              void* d_out, int out_size, void* d_ws, size_t ws_size,
                              hipStream_t stream) {
  const float* x     = (const float*)d_in[0];
  const float* Wqkv  = (const float*)d_in[1];
  const float* Wproj = (const float*)d_in[2];
  const float* bproj = (const float*)d_in[3];
  float* out = (float*)d_out;

  // workspace layout (~122 MB total)
  char* ws = (char*)d_ws;
  float* QKV = (float*)ws;                       size_t off = (size_t)4096 * 3456 * 4;
  short* xb  = (short*)(ws + off);  off += (size_t)4096 * 1152 * 2;
  short* Wt  = (short*)(ws + off);  off += (size_t)3456 * 1152 * 2;
  short* Wpt = (short*)(ws + off);  off += (size_t)1152 * 1152 * 2;
  short* Qp  = (short*)(ws + off);  off += (size_t)B_ * NH * N_ * HDP * 2;
  short* Kp  = (short*)(ws + off);  off += (size_t)B_ * NH * N_ * HDP * 2;
  short* Vt  = (short*)(ws + off);  off += (size_t)B_ * NH * HDV * N_ * 2;
  short* Ap  = (short*)(ws + off);  off += (size_t)4096 * 1152 * 2;

  cvt_bf16<<<(4096 * 1152 / 4 + 255) / 256, 256, 0, stream>>>(x, xb, 4096 * 1152 / 4);
  transpose_cvt<<<dim3(3456 / 32, 1152 / 32), dim3(32, 8), 0, stream>>>(Wqkv, Wt, 1152, 3456);
  transpose_cvt<<<dim3(1152 / 32, 1152 / 32), dim3(32, 8), 0, stream>>>(Wproj, Wpt, 1152, 1152);
  gemm_bt<false><<<dim3(3456 / 128, 4096 / 128), 256, 0, stream>>>(
      xb, Wt, QKV, nullptr, 4096, 3456, 1152);
  rope_pack<<<B_ * NH * (N_ / 128), 256, 0, stream>>>(QKV, Qp, Kp, Vt);
  attn<<<B_ * NH * (N_ / 128), 256, 0, stream>>>(Qp, Kp, Vt, Ap);
  gemm_bt<true><<<dim3(1152 / 128, 4096 / 128), 256, 0, stream>>>(
      Ap, Wpt, out, bproj, 4096, 1152, 1152);
}